// Round 9
// baseline (166.934 us; speedup 1.0000x reference)
//
#include <hip/hip_runtime.h>

#define BB 4
#define SS 2048
#define DD 64
#define HH 16
#define HDD 4
#define NBH (BB*HH)          // 64 (b,h) pairs
#define NROWS (BB*SS)        // 8192
#define NQ (NBH*SS)          // 131072 query rows
#define QTILES 8             // SS/256 (combine grid)
#define CNBLK (NBH*QTILES)   // 512 combine blocks (2/CU -> co-resident)
#define LOG2E_HALF 0.7213475204444817f  // log2(e)*0.5 (1/sqrt(HD) folded into K)

// native 2-wide fp32 vector: compiler lowers fma on this to v_pk_fma_f32
typedef float f32x2 __attribute__((ext_vector_type(2)));

// ---------------- Kernel 1: QKV projection + ReLU (R6 scalar version) ------
// Q -> [bh][s][4].  K,V -> pair-transposed KV[bh][s/2][16]. K prescaled by
// log2(e)/2. Also resets the combine kernel's barrier counter each call.
__global__ __launch_bounds__(256) void qkv_kernel(
    const float* __restrict__ x,
    const float* __restrict__ Wq, const float* __restrict__ bq,
    const float* __restrict__ Wk, const float* __restrict__ bk,
    const float* __restrict__ Wv, const float* __restrict__ bv,
    float* __restrict__ Q, float* __restrict__ KV,
    unsigned int* __restrict__ counter)
{
    if (blockIdx.x == 0 && threadIdx.x == 0)
        __hip_atomic_store(counter, 0u, __ATOMIC_RELAXED, __HIP_MEMORY_SCOPE_AGENT);

    __shared__ float xs[4 * 64];
    const int tid = threadIdx.x;
    const int row0 = blockIdx.x * 4;

    xs[tid] = x[(size_t)row0 * 64 + tid];
    __syncthreads();

    const int r = tid >> 6;
    const int c = tid & 63;
    const int row = row0 + r;
    const int b = row >> 11;
    const int s = row & (SS - 1);
    const float* xr = &xs[r * 64];

    float aq = bq[c], ak = bk[c], av = bv[c];
    #pragma unroll 16
    for (int k = 0; k < 64; ++k) {
        const float xv = xr[k];
        aq = fmaf(xv, Wq[k * 64 + c], aq);
        ak = fmaf(xv, Wk[k * 64 + c], ak);
        av = fmaf(xv, Wv[k * 64 + c], av);
    }
    aq = fmaxf(aq, 0.0f);
    ak = fmaxf(ak, 0.0f) * LOG2E_HALF;
    av = fmaxf(av, 0.0f);

    const int h = c >> 2, hd = c & 3;
    const size_t bhs = ((size_t)(b * HH + h) * SS + s);
    Q[bhs * 4 + hd] = aq;

    const int p = s >> 1, po = s & 1;
    const size_t pb = ((size_t)(b * HH + h) * (SS / 2) + p) * 16;
    KV[pb + hd * 2 + po] = ak;
    KV[pb + 8 + hd * 2 + po] = av;
}

// ---------------- Kernel 2: attention (unchanged from R6) ------------------
template<int KSPLIT, int QROWS, bool DIRECT>
__global__ __launch_bounds__(256) void attn_kernel(
    const float* __restrict__ Qb, const float* __restrict__ KVb,
    const float* __restrict__ x, float* __restrict__ y,
    float* __restrict__ accS, float* __restrict__ sumS)
{
    constexpr int QT = SS / (256 * QROWS);   // q-tiles per bh
    const int tid = threadIdx.x;
    int blk = blockIdx.x;
    const int ks = blk / (NBH * QT);
    blk -= ks * (NBH * QT);
    const int bh = blk / QT;
    const int qt = blk - bh * QT;

    const int PAIRS = SS / 2 / KSPLIT;
    const f32x2* kv = (const f32x2*)(KVb + ((size_t)bh * (SS / 2) + (size_t)ks * PAIRS) * 16);

    f32x2 qx[QROWS], qy[QROWS], qz[QROWS], qw[QROWS];
    #pragma unroll
    for (int r = 0; r < QROWS; ++r) {
        const int qrow = qt * (256 * QROWS) + r * 256 + tid;
        const float4 q = ((const float4*)Qb)[(size_t)bh * SS + qrow];
        qx[r] = {q.x, q.x}; qy[r] = {q.y, q.y};
        qz[r] = {q.z, q.z}; qw[r] = {q.w, q.w};
    }

    f32x2 acx[QROWS], acy[QROWS], acz[QROWS], acw[QROWS], sm[QROWS];
    #pragma unroll
    for (int r = 0; r < QROWS; ++r) {
        acx[r] = {0.f, 0.f}; acy[r] = {0.f, 0.f};
        acz[r] = {0.f, 0.f}; acw[r] = {0.f, 0.f};
        sm[r] = {0.f, 0.f};
    }

    #pragma unroll 2
    for (int j = 0; j < PAIRS; ++j) {
        const f32x2 kx = kv[j * 8 + 0];   // uniform -> scalar loads
        const f32x2 ky = kv[j * 8 + 1];
        const f32x2 kz = kv[j * 8 + 2];
        const f32x2 kw = kv[j * 8 + 3];
        const f32x2 vx = kv[j * 8 + 4];
        const f32x2 vy = kv[j * 8 + 5];
        const f32x2 vz = kv[j * 8 + 6];
        const f32x2 vw = kv[j * 8 + 7];
        #pragma unroll
        for (int r = 0; r < QROWS; ++r) {
            f32x2 s = qx[r] * kx;
            s = __builtin_elementwise_fma(qy[r], ky, s);
            s = __builtin_elementwise_fma(qz[r], kz, s);
            s = __builtin_elementwise_fma(qw[r], kw, s);
            f32x2 e;
            e.x = __builtin_amdgcn_exp2f(s.x);
            e.y = __builtin_amdgcn_exp2f(s.y);
            sm[r] += e;
            acx[r] = __builtin_elementwise_fma(e, vx, acx[r]);
            acy[r] = __builtin_elementwise_fma(e, vy, acy[r]);
            acz[r] = __builtin_elementwise_fma(e, vz, acz[r]);
            acw[r] = __builtin_elementwise_fma(e, vw, acw[r]);
        }
    }

    #pragma unroll
    for (int r = 0; r < QROWS; ++r) {
        const int qrow = qt * (256 * QROWS) + r * 256 + tid;
        const float sum = sm[r].x + sm[r].y;
        float4 acc = {acx[r].x + acx[r].y, acy[r].x + acy[r].y,
                      acz[r].x + acz[r].y, acw[r].x + acw[r].y};
        if (DIRECT) {
            const float inv = 1.0f / sum;
            const int b = bh >> 4, h = bh & 15;
            const size_t o = ((size_t)(b * SS + qrow)) * DD + h * HDD;
            const float4 xr = *(const float4*)(x + o);
            float4 out;
            out.x = fmaf(acc.x, inv, xr.x);
            out.y = fmaf(acc.y, inv, xr.y);
            out.z = fmaf(acc.z, inv, xr.z);
            out.w = fmaf(acc.w, inv, xr.w);
            *(float4*)(y + o) = out;
        } else {
            const size_t qi = (size_t)ks * NQ + (size_t)bh * SS + qrow;
            ((float4*)accS)[qi] = acc;
            sumS[qi] = sum;
        }
    }
}

// ---------------- Kernel 3: combine + residual + BN (single kernel) --------
// Phase 1: combine KSPLIT partials, add residual, keep `out` IN REGISTERS,
//   block-reduce per-channel sum/sumsq -> part2 via agent-scope stores.
// Device-wide barrier: atomic counter + spin (512 blocks = 2/CU, co-resident;
//   agent-scope atomics are the cross-XCD-safe primitive per guide G16).
// Phase 2: re-read 256 floats of part2, compute this head's 4-channel stats,
//   normalize the register-held out, single y write.
template<int KSPLIT>
__global__ __launch_bounds__(256, 2) void combine_bn_norm(
    const float* __restrict__ accS, const float* __restrict__ sumS,
    const float* __restrict__ x, float* __restrict__ y,
    float* __restrict__ part2, unsigned int* __restrict__ counter,
    const float* __restrict__ gamma, const float* __restrict__ beta)
{
    __shared__ float rr[4][8];
    __shared__ float st8[8];
    const int tid = threadIdx.x;
    const int bh = blockIdx.x >> 3;
    const int qt = blockIdx.x & 7;
    const int qrow = qt * 256 + tid;
    const size_t qi = (size_t)bh * SS + qrow;

    float4 a = ((const float4*)accS)[qi];
    float s = sumS[qi];
    #pragma unroll
    for (int k = 1; k < KSPLIT; ++k) {
        const float4 a2 = ((const float4*)accS)[(size_t)k * NQ + qi];
        a.x += a2.x; a.y += a2.y; a.z += a2.z; a.w += a2.w;
        s += sumS[(size_t)k * NQ + qi];
    }
    const float inv = 1.0f / s;
    const int b = bh >> 4, h = bh & 15;
    const size_t o = ((size_t)(b * SS + qrow)) * DD + h * HDD;
    const float4 xr = *(const float4*)(x + o);
    float4 out;
    out.x = fmaf(a.x, inv, xr.x);
    out.y = fmaf(a.y, inv, xr.y);
    out.z = fmaf(a.z, inv, xr.z);
    out.w = fmaf(a.w, inv, xr.w);

    // per-channel sum / sumsq over this block's 256 rows (4 channels of head h)
    float v[8] = {out.x, out.y, out.z, out.w,
                  out.x * out.x, out.y * out.y, out.z * out.z, out.w * out.w};
    #pragma unroll
    for (int i = 0; i < 8; ++i) {
        float t = v[i];
        for (int off = 32; off > 0; off >>= 1) t += __shfl_down(t, off);
        v[i] = t;
    }
    const int wid = tid >> 6;
    if ((tid & 63) == 0) {
        #pragma unroll
        for (int i = 0; i < 8; ++i) rr[wid][i] = v[i];
    }
    __syncthreads();
    if (tid < 8) {
        const float t = rr[0][tid] + rr[1][tid] + rr[2][tid] + rr[3][tid];
        const int slot = b * 8 + qt;                 // 32 slots per channel
        const int i = tid & 3;
        const int c = h * 4 + i;
        float* dst = (tid < 4) ? &part2[c * 32 + slot]
                               : &part2[2048 + c * 32 + slot];
        __hip_atomic_store(dst, t, __ATOMIC_RELAXED, __HIP_MEMORY_SCOPE_AGENT);
    }
    __threadfence();
    __syncthreads();

    // ---- device-wide barrier ----
    if (tid == 0) {
        __hip_atomic_fetch_add(counter, 1u, __ATOMIC_ACQ_REL, __HIP_MEMORY_SCOPE_AGENT);
        while (__hip_atomic_load(counter, __ATOMIC_ACQUIRE, __HIP_MEMORY_SCOPE_AGENT) < (unsigned)CNBLK) {}
    }
    __syncthreads();

    // ---- phase 2: stats for this head's 4 channels ----
    if (tid < 8) {
        const int i = tid & 3;
        const int reg = tid >> 2;                    // 0=sum, 1=sumsq
        const float* p = part2 + reg * 2048 + (h * 4 + i) * 32;
        float acc2 = 0.f;
        #pragma unroll
        for (int k = 0; k < 32; ++k)
            acc2 += __hip_atomic_load(p + k, __ATOMIC_RELAXED, __HIP_MEMORY_SCOPE_AGENT);
        st8[tid] = acc2;
    }
    __syncthreads();

    const float n = 1.0f / NROWS;
    const int c0 = h * 4;
    const float m0 = st8[0] * n, m1 = st8[1] * n, m2 = st8[2] * n, m3 = st8[3] * n;
    const float r0 = rsqrtf(st8[4] * n - m0 * m0 + 1e-5f);
    const float r1 = rsqrtf(st8[5] * n - m1 * m1 + 1e-5f);
    const float r2 = rsqrtf(st8[6] * n - m2 * m2 + 1e-5f);
    const float r3 = rsqrtf(st8[7] * n - m3 * m3 + 1e-5f);
    out.x = fmaf((out.x - m0) * r0, gamma[c0],     beta[c0]);
    out.y = fmaf((out.y - m1) * r1, gamma[c0 + 1], beta[c0 + 1]);
    out.z = fmaf((out.z - m2) * r2, gamma[c0 + 2], beta[c0 + 2]);
    out.w = fmaf((out.w - m3) * r3, gamma[c0 + 3], beta[c0 + 3]);
    *(float4*)(y + o) = out;
}

// ---------------- Fallback BN chain (tiny-workspace path only) -------------
__global__ __launch_bounds__(256) void bn_reduce1(
    const float* __restrict__ y, float* __restrict__ part)
{
    __shared__ float ls[256], ls2[256];
    const int tid = threadIdx.x;
    const int c = tid & 63;
    const int rg = tid >> 6;
    const int row0 = blockIdx.x * 32 + rg * 8;
    float s = 0.0f, s2 = 0.0f;
    #pragma unroll
    for (int i = 0; i < 8; ++i) {
        const float v = y[(size_t)(row0 + i) * 64 + c];
        s += v;
        s2 = fmaf(v, v, s2);
    }
    ls[tid] = s; ls2[tid] = s2;
    __syncthreads();
    if (rg == 0) {
        part[blockIdx.x * 64 + c] = ls[c] + ls[64 + c] + ls[128 + c] + ls[192 + c];
        part[256 * 64 + blockIdx.x * 64 + c] = ls2[c] + ls2[64 + c] + ls2[128 + c] + ls2[192 + c];
    }
}

__global__ __launch_bounds__(256) void bn_reduce2(
    const float* __restrict__ part, float* __restrict__ stats)
{
    __shared__ float ls[256], ls2[256];
    const int tid = threadIdx.x;
    const int c = tid & 63;
    const int pg = tid >> 6;
    float s = 0.0f, s2 = 0.0f;
    for (int i = pg; i < 256; i += 4) {
        s  += part[i * 64 + c];
        s2 += part[256 * 64 + i * 64 + c];
    }
    ls[tid] = s; ls2[tid] = s2;
    __syncthreads();
    if (pg == 0) {
        const float ts  = ls[c]  + ls[64 + c]  + ls[128 + c]  + ls[192 + c];
        const float ts2 = ls2[c] + ls2[64 + c] + ls2[128 + c] + ls2[192 + c];
        const float mean = ts * (1.0f / NROWS);
        const float var  = ts2 * (1.0f / NROWS) - mean * mean;
        stats[c] = mean;
        stats[64 + c] = rsqrtf(var + 1e-5f);
    }
}

__global__ __launch_bounds__(256) void bn_norm(
    float* __restrict__ y, const float* __restrict__ stats,
    const float* __restrict__ gamma, const float* __restrict__ beta)
{
    const int idx = blockIdx.x * 256 + threadIdx.x;
    const int c = idx & 63;
    const float v = y[idx];
    y[idx] = fmaf((v - stats[c]) * stats[64 + c], gamma[c], beta[c]);
}

// ---------------------------------------------------------------------------
extern "C" void kernel_launch(void* const* d_in, const int* in_sizes, int n_in,
                              void* d_out, int out_size, void* d_ws, size_t ws_size,
                              hipStream_t stream)
{
    const float* x     = (const float*)d_in[0];
    const float* Wq    = (const float*)d_in[1];
    const float* bq    = (const float*)d_in[2];
    const float* Wk    = (const float*)d_in[3];
    const float* bk    = (const float*)d_in[4];
    const float* Wv    = (const float*)d_in[5];
    const float* bv    = (const float*)d_in[6];
    const float* gamma = (const float*)d_in[7];
    const float* beta  = (const float*)d_in[8];
    float* out = (float*)d_out;

    float* ws = (float*)d_ws;
    float* Q  = ws;                  // 524288 floats (2 MB)
    float* KV = ws + 524288;         // 1048576 floats (4 MB)

    const size_t base = 524288 + 1048576;
    auto need = [](int kk) {
        return (size_t)(524288 + 1048576 + (size_t)kk * NQ * 5 + 4096 + 128) * 4;
    };
    constexpr int QR = 2;                      // query rows per thread
    constexpr int QT = SS / (256 * QR);        // 4 q-tiles per bh

    if (ws_size >= need(8)) {
        float* accS  = ws + base;
        float* sumS  = accS + (size_t)8 * NQ * 4;
        float* part2 = sumS + (size_t)8 * NQ;
        unsigned int* counter = (unsigned int*)(part2 + 4096);
        qkv_kernel<<<NROWS / 4, 256, 0, stream>>>(x, Wq, bq, Wk, bk, Wv, bv, Q, KV, counter);
        attn_kernel<8, QR, false><<<8 * NBH * QT, 256, 0, stream>>>(Q, KV, x, out, accS, sumS);
        combine_bn_norm<8><<<CNBLK, 256, 0, stream>>>(accS, sumS, x, out, part2, counter, gamma, beta);
    } else if (ws_size >= need(4)) {
        float* accS  = ws + base;
        float* sumS  = accS + (size_t)4 * NQ * 4;
        float* part2 = sumS + (size_t)4 * NQ;
        unsigned int* counter = (unsigned int*)(part2 + 4096);
        qkv_kernel<<<NROWS / 4, 256, 0, stream>>>(x, Wq, bq, Wk, bk, Wv, bv, Q, KV, counter);
        attn_kernel<4, QR, false><<<4 * NBH * QT, 256, 0, stream>>>(Q, KV, x, out, accS, sumS);
        combine_bn_norm<4><<<CNBLK, 256, 0, stream>>>(accS, sumS, x, out, part2, counter, gamma, beta);
    } else if (ws_size >= need(2)) {
        float* accS  = ws + base;
        float* sumS  = accS + (size_t)2 * NQ * 4;
        float* part2 = sumS + (size_t)2 * NQ;
        unsigned int* counter = (unsigned int*)(part2 + 4096);
        qkv_kernel<<<NROWS / 4, 256, 0, stream>>>(x, Wq, bq, Wk, bk, Wv, bv, Q, KV, counter);
        attn_kernel<2, QR, false><<<2 * NBH * QT, 256, 0, stream>>>(Q, KV, x, out, accS, sumS);
        combine_bn_norm<2><<<CNBLK, 256, 0, stream>>>(accS, sumS, x, out, part2, counter, gamma, beta);
    } else {
        float* part  = ws + base;                      // 32768 floats
        float* stats = part + 32768;                   // 128
        unsigned int* counter = (unsigned int*)(stats + 128);
        qkv_kernel<<<NROWS / 4, 256, 0, stream>>>(x, Wq, bq, Wk, bk, Wv, bv, Q, KV, counter);
        attn_kernel<1, QR, true><<<NBH * QT, 256, 0, stream>>>(Q, KV, x, out, nullptr, nullptr);
        bn_reduce1<<<256, 256, 0, stream>>>(out, part);
        bn_reduce2<<<1, 256, 0, stream>>>(part, stats);
        bn_norm<<<NROWS * DD / 256, 256, 0, stream>>>(out, stats, gamma, beta);
    }
}

// Round 10
// 111.113 us; speedup vs baseline: 1.5024x; 1.5024x over previous
//
#include <hip/hip_runtime.h>

#define BB 4
#define SS 2048
#define DD 64
#define HH 16
#define HDD 4
#define NBH (BB*HH)          // 64 (b,h) pairs
#define NROWS (BB*SS)        // 8192
#define NQ (NBH*SS)          // 131072 query rows
#define QTILES 8             // SS/256 (for combine kernel)
#define LOG2E_HALF 0.7213475204444817f  // log2(e)*0.5 (1/sqrt(HD) folded into K)

// native 2-wide fp32 vector: compiler lowers fma on this to v_pk_fma_f32
// (gfx90a+ packed-FP32), inserting required hazard wait-states itself.
typedef float f32x2 __attribute__((ext_vector_type(2)));

// ---------------- Kernel 1: QKV projection + ReLU (R6 scalar version) ------
// Q -> [bh][s][4].  K,V -> pair-transposed KV[bh][s/2][16]:
//   {k0x,k1x, k0y,k1y, k0z,k1z, k0w,k1w, v0x,v1x, ..., v0w,v1w}
// K is prescaled by log2(e)/2.
__global__ __launch_bounds__(256) void qkv_kernel(
    const float* __restrict__ x,
    const float* __restrict__ Wq, const float* __restrict__ bq,
    const float* __restrict__ Wk, const float* __restrict__ bk,
    const float* __restrict__ Wv, const float* __restrict__ bv,
    float* __restrict__ Q, float* __restrict__ KV)
{
    __shared__ float xs[4 * 64];
    const int tid = threadIdx.x;
    const int row0 = blockIdx.x * 4;

    xs[tid] = x[(size_t)row0 * 64 + tid];
    __syncthreads();

    const int r = tid >> 6;
    const int c = tid & 63;
    const int row = row0 + r;
    const int b = row >> 11;
    const int s = row & (SS - 1);
    const float* xr = &xs[r * 64];

    float aq = bq[c], ak = bk[c], av = bv[c];
    #pragma unroll 16
    for (int k = 0; k < 64; ++k) {
        const float xv = xr[k];
        aq = fmaf(xv, Wq[k * 64 + c], aq);
        ak = fmaf(xv, Wk[k * 64 + c], ak);
        av = fmaf(xv, Wv[k * 64 + c], av);
    }
    aq = fmaxf(aq, 0.0f);
    ak = fmaxf(ak, 0.0f) * LOG2E_HALF;   // fold softmax scale+log2e into K
    av = fmaxf(av, 0.0f);

    const int h = c >> 2, hd = c & 3;
    const size_t bhs = ((size_t)(b * HH + h) * SS + s);
    Q[bhs * 4 + hd] = aq;

    const int p = s >> 1, po = s & 1;
    const size_t pb = ((size_t)(b * HH + h) * (SS / 2) + p) * 16;
    KV[pb + hd * 2 + po] = ak;
    KV[pb + 8 + hd * 2 + po] = av;
}

// ---------------- Kernel 2: attention (LDS-staged KV chunk) ----------------
// Per-block KV chunk (PAIRS*64 B; 8 KB at KSPLIT=8) is staged into LDS with
// coalesced float4 loads, then the inner loop reads it with broadcast LDS
// reads (all lanes same address -> bank broadcast, no conflicts). Removes
// the per-iter global/scalar-load latency from the loop entirely.
// QROWS query rows per thread; packed-fp32 math; no max-subtraction
// (relu'd inputs, HD=4: scores bounded, exp2 safe in fp32).
template<int KSPLIT, int QROWS, bool DIRECT>
__global__ __launch_bounds__(256) void attn_kernel(
    const float* __restrict__ Qb, const float* __restrict__ KVb,
    const float* __restrict__ x, float* __restrict__ y,
    float* __restrict__ accS, float* __restrict__ sumS)
{
    constexpr int QT = SS / (256 * QROWS);   // q-tiles per bh
    constexpr int PAIRS = SS / 2 / KSPLIT;
    __shared__ float4 kvs4[PAIRS * 4];       // PAIRS*64 bytes
    const f32x2* kvs = (const f32x2*)kvs4;

    const int tid = threadIdx.x;
    int blk = blockIdx.x;
    const int ks = blk / (NBH * QT);
    blk -= ks * (NBH * QT);
    const int bh = blk / QT;
    const int qt = blk - bh * QT;

    const float4* kvg = (const float4*)(KVb + ((size_t)bh * (SS / 2) + (size_t)ks * PAIRS) * 16);
    #pragma unroll
    for (int i = 0; i < PAIRS * 4 / 256; ++i)
        kvs4[i * 256 + tid] = kvg[i * 256 + tid];

    f32x2 qx[QROWS], qy[QROWS], qz[QROWS], qw[QROWS];
    #pragma unroll
    for (int r = 0; r < QROWS; ++r) {
        const int qrow = qt * (256 * QROWS) + r * 256 + tid;
        const float4 q = ((const float4*)Qb)[(size_t)bh * SS + qrow];
        qx[r] = {q.x, q.x}; qy[r] = {q.y, q.y};
        qz[r] = {q.z, q.z}; qw[r] = {q.w, q.w};
    }

    f32x2 acx[QROWS], acy[QROWS], acz[QROWS], acw[QROWS], sm[QROWS];
    #pragma unroll
    for (int r = 0; r < QROWS; ++r) {
        acx[r] = {0.f, 0.f}; acy[r] = {0.f, 0.f};
        acz[r] = {0.f, 0.f}; acw[r] = {0.f, 0.f};
        sm[r] = {0.f, 0.f};
    }

    __syncthreads();

    #pragma unroll 2
    for (int j = 0; j < PAIRS; ++j) {
        const f32x2 kx = kvs[j * 8 + 0];   // broadcast LDS reads
        const f32x2 ky = kvs[j * 8 + 1];
        const f32x2 kz = kvs[j * 8 + 2];
        const f32x2 kw = kvs[j * 8 + 3];
        const f32x2 vx = kvs[j * 8 + 4];
        const f32x2 vy = kvs[j * 8 + 5];
        const f32x2 vz = kvs[j * 8 + 6];
        const f32x2 vw = kvs[j * 8 + 7];
        #pragma unroll
        for (int r = 0; r < QROWS; ++r) {
            f32x2 s = qx[r] * kx;
            s = __builtin_elementwise_fma(qy[r], ky, s);
            s = __builtin_elementwise_fma(qz[r], kz, s);
            s = __builtin_elementwise_fma(qw[r], kw, s);
            f32x2 e;
            e.x = __builtin_amdgcn_exp2f(s.x);
            e.y = __builtin_amdgcn_exp2f(s.y);
            sm[r] += e;
            acx[r] = __builtin_elementwise_fma(e, vx, acx[r]);
            acy[r] = __builtin_elementwise_fma(e, vy, acy[r]);
            acz[r] = __builtin_elementwise_fma(e, vz, acz[r]);
            acw[r] = __builtin_elementwise_fma(e, vw, acw[r]);
        }
    }

    #pragma unroll
    for (int r = 0; r < QROWS; ++r) {
        const int qrow = qt * (256 * QROWS) + r * 256 + tid;
        const float sum = sm[r].x + sm[r].y;
        float4 acc = {acx[r].x + acx[r].y, acy[r].x + acy[r].y,
                      acz[r].x + acz[r].y, acw[r].x + acw[r].y};
        if (DIRECT) {
            const float inv = 1.0f / sum;
            const int b = bh >> 4, h = bh & 15;
            const size_t o = ((size_t)(b * SS + qrow)) * DD + h * HDD;
            const float4 xr = *(const float4*)(x + o);
            float4 out;
            out.x = fmaf(acc.x, inv, xr.x);
            out.y = fmaf(acc.y, inv, xr.y);
            out.z = fmaf(acc.z, inv, xr.z);
            out.w = fmaf(acc.w, inv, xr.w);
            *(float4*)(y + o) = out;
        } else {
            const size_t qi = (size_t)ks * NQ + (size_t)bh * SS + qrow;
            ((float4*)accS)[qi] = acc;
            sumS[qi] = sum;
        }
    }
}

// ---------------- Kernel 3: combine partials + residual + BN partials ------
template<int KSPLIT>
__global__ __launch_bounds__(256) void combine_bn(
    const float* __restrict__ accS, const float* __restrict__ sumS,
    const float* __restrict__ x, float* __restrict__ y,
    float* __restrict__ part2)
{
    __shared__ float r[4][8];
    const int tid = threadIdx.x;
    const int bh = blockIdx.x >> 3;
    const int qt = blockIdx.x & 7;
    const int qrow = qt * 256 + tid;
    const size_t qi = (size_t)bh * SS + qrow;

    float4 a = ((const float4*)accS)[qi];
    float s = sumS[qi];
    #pragma unroll
    for (int k = 1; k < KSPLIT; ++k) {
        const float4 a2 = ((const float4*)accS)[(size_t)k * NQ + qi];
        a.x += a2.x; a.y += a2.y; a.z += a2.z; a.w += a2.w;
        s += sumS[(size_t)k * NQ + qi];
    }
    const float inv = 1.0f / s;
    const int b = bh >> 4, h = bh & 15;
    const size_t o = ((size_t)(b * SS + qrow)) * DD + h * HDD;
    const float4 xr = *(const float4*)(x + o);
    float4 out;
    out.x = fmaf(a.x, inv, xr.x);
    out.y = fmaf(a.y, inv, xr.y);
    out.z = fmaf(a.z, inv, xr.z);
    out.w = fmaf(a.w, inv, xr.w);
    *(float4*)(y + o) = out;

    float v[8] = {out.x, out.y, out.z, out.w,
                  out.x * out.x, out.y * out.y, out.z * out.z, out.w * out.w};
    #pragma unroll
    for (int i = 0; i < 8; ++i) {
        float t = v[i];
        for (int off = 32; off > 0; off >>= 1) t += __shfl_down(t, off);
        v[i] = t;
    }
    const int wid = tid >> 6;
    if ((tid & 63) == 0) {
        #pragma unroll
        for (int i = 0; i < 8; ++i) r[wid][i] = v[i];
    }
    __syncthreads();
    if (tid < 8) {
        const float t = r[0][tid] + r[1][tid] + r[2][tid] + r[3][tid];
        const int slot = b * 8 + qt;
        const int i = tid & 3;
        const int c = h * 4 + i;
        if (tid < 4) part2[c * 32 + slot] = t;
        else         part2[2048 + c * 32 + slot] = t;
    }
}

// ---------------- Kernel 4: fused BN stats + normalize ---------------------
__global__ __launch_bounds__(256) void bn_norm_fused(
    float* __restrict__ y, const float* __restrict__ part2,
    const float* __restrict__ gamma, const float* __restrict__ beta)
{
    __shared__ float st[128];
    const int tid = threadIdx.x;
    if (tid < 128) {
        const int c = tid & 63;
        const float* p = part2 + (tid >> 6) * 2048 + c * 32;
        float s = 0.f;
        #pragma unroll
        for (int i = 0; i < 32; ++i) s += p[i];
        st[tid] = s;
    }
    __syncthreads();

    const int idx = blockIdx.x * 256 + tid;          // float4 index
    const int c0 = (idx & 15) * 4;
    float4 v = ((const float4*)y)[idx];
    const float n = 1.0f / NROWS;
    const float m0 = st[c0] * n,     m1 = st[c0 + 1] * n;
    const float m2 = st[c0 + 2] * n, m3 = st[c0 + 3] * n;
    const float r0 = rsqrtf(st[64 + c0] * n - m0 * m0 + 1e-5f);
    const float r1 = rsqrtf(st[65 + c0] * n - m1 * m1 + 1e-5f);
    const float r2 = rsqrtf(st[66 + c0] * n - m2 * m2 + 1e-5f);
    const float r3 = rsqrtf(st[67 + c0] * n - m3 * m3 + 1e-5f);
    float4 o;
    o.x = fmaf((v.x - m0) * r0, gamma[c0],     beta[c0]);
    o.y = fmaf((v.y - m1) * r1, gamma[c0 + 1], beta[c0 + 1]);
    o.z = fmaf((v.z - m2) * r2, gamma[c0 + 2], beta[c0 + 2]);
    o.w = fmaf((v.w - m3) * r3, gamma[c0 + 3], beta[c0 + 3]);
    ((float4*)y)[idx] = o;
}

// ---------------- Fallback BN reduce (tiny-workspace path) -----------------
__global__ __launch_bounds__(256) void bn_reduce1(
    const float* __restrict__ y, float* __restrict__ part)
{
    __shared__ float ls[256], ls2[256];
    const int tid = threadIdx.x;
    const int c = tid & 63;
    const int rg = tid >> 6;
    const int row0 = blockIdx.x * 32 + rg * 8;
    float s = 0.0f, s2 = 0.0f;
    #pragma unroll
    for (int i = 0; i < 8; ++i) {
        const float v = y[(size_t)(row0 + i) * 64 + c];
        s += v;
        s2 = fmaf(v, v, s2);
    }
    ls[tid] = s; ls2[tid] = s2;
    __syncthreads();
    if (rg == 0) {
        part[blockIdx.x * 64 + c] = ls[c] + ls[64 + c] + ls[128 + c] + ls[192 + c];
        part[256 * 64 + blockIdx.x * 64 + c] = ls2[c] + ls2[64 + c] + ls2[128 + c] + ls2[192 + c];
    }
}

__global__ __launch_bounds__(256) void bn_reduce2(
    const float* __restrict__ part, float* __restrict__ stats)
{
    __shared__ float ls[256], ls2[256];
    const int tid = threadIdx.x;
    const int c = tid & 63;
    const int pg = tid >> 6;
    float s = 0.0f, s2 = 0.0f;
    for (int i = pg; i < 256; i += 4) {
        s  += part[i * 64 + c];
        s2 += part[256 * 64 + i * 64 + c];
    }
    ls[tid] = s; ls2[tid] = s2;
    __syncthreads();
    if (pg == 0) {
        const float ts  = ls[c]  + ls[64 + c]  + ls[128 + c]  + ls[192 + c];
        const float ts2 = ls2[c] + ls2[64 + c] + ls2[128 + c] + ls2[192 + c];
        const float mean = ts * (1.0f / NROWS);
        const float var  = ts2 * (1.0f / NROWS) - mean * mean;
        stats[c] = mean;
        stats[64 + c] = rsqrtf(var + 1e-5f);
    }
}

__global__ __launch_bounds__(256) void bn_norm(
    float* __restrict__ y, const float* __restrict__ stats,
    const float* __restrict__ gamma, const float* __restrict__ beta)
{
    const int idx = blockIdx.x * 256 + threadIdx.x;
    const int c = idx & 63;
    const float v = y[idx];
    y[idx] = fmaf((v - stats[c]) * stats[64 + c], gamma[c], beta[c]);
}

// ---------------------------------------------------------------------------
extern "C" void kernel_launch(void* const* d_in, const int* in_sizes, int n_in,
                              void* d_out, int out_size, void* d_ws, size_t ws_size,
                              hipStream_t stream)
{
    const float* x     = (const float*)d_in[0];
    const float* Wq    = (const float*)d_in[1];
    const float* bq    = (const float*)d_in[2];
    const float* Wk    = (const float*)d_in[3];
    const float* bk    = (const float*)d_in[4];
    const float* Wv    = (const float*)d_in[5];
    const float* bv    = (const float*)d_in[6];
    const float* gamma = (const float*)d_in[7];
    const float* beta  = (const float*)d_in[8];
    float* out = (float*)d_out;

    float* ws = (float*)d_ws;
    float* Q  = ws;                  // 524288 floats (2 MB)
    float* KV = ws + 524288;         // 1048576 floats (4 MB)

    qkv_kernel<<<NROWS / 4, 256, 0, stream>>>(x, Wq, bq, Wk, bk, Wv, bv, Q, KV);

    const size_t base = 524288 + 1048576;
    auto need = [](int kk) {
        return (size_t)(524288 + 1048576 + (size_t)kk * NQ * 5 + 4096 + 128) * 4;
    };
    constexpr int QR = 2;                      // query rows per thread
    constexpr int QT = SS / (256 * QR);        // 4 q-tiles per bh

    if (ws_size >= need(8)) {
        // 8-way key split: 2048 blocks, 8 KB LDS KV chunk per block
        float* accS  = ws + base;
        float* sumS  = accS + (size_t)8 * NQ * 4;
        float* part2 = sumS + (size_t)8 * NQ;
        attn_kernel<8, QR, false><<<8 * NBH * QT, 256, 0, stream>>>(Q, KV, x, out, accS, sumS);
        combine_bn<8><<<NBH * QTILES, 256, 0, stream>>>(accS, sumS, x, out, part2);
        bn_norm_fused<<<NROWS * DD / 1024, 256, 0, stream>>>(out, part2, gamma, beta);
    } else if (ws_size >= need(4)) {
        float* accS  = ws + base;
        float* sumS  = accS + (size_t)4 * NQ * 4;
        float* part2 = sumS + (size_t)4 * NQ;
        attn_kernel<4, QR, false><<<4 * NBH * QT, 256, 0, stream>>>(Q, KV, x, out, accS, sumS);
        combine_bn<4><<<NBH * QTILES, 256, 0, stream>>>(accS, sumS, x, out, part2);
        bn_norm_fused<<<NROWS * DD / 1024, 256, 0, stream>>>(out, part2, gamma, beta);
    } else if (ws_size >= need(2)) {
        float* accS  = ws + base;
        float* sumS  = accS + (size_t)2 * NQ * 4;
        float* part2 = sumS + (size_t)2 * NQ;
        attn_kernel<2, QR, false><<<2 * NBH * QT, 256, 0, stream>>>(Q, KV, x, out, accS, sumS);
        combine_bn<2><<<NBH * QTILES, 256, 0, stream>>>(accS, sumS, x, out, part2);
        bn_norm_fused<<<NROWS * DD / 1024, 256, 0, stream>>>(out, part2, gamma, beta);
    } else {
        float* part  = ws + base;                      // 32768 floats
        float* stats = part + 32768;                   // 128
        attn_kernel<1, QR, true><<<NBH * QT, 256, 0, stream>>>(Q, KV, x, out, nullptr, nullptr);
        bn_reduce1<<<256, 256, 0, stream>>>(out, part);
        bn_reduce2<<<1, 256, 0, stream>>>(part, stats);
        bn_norm<<<NROWS * DD / 256, 256, 0, stream>>>(out, stats, gamma, beta);
    }
}

// Round 11
// 110.642 us; speedup vs baseline: 1.5088x; 1.0043x over previous
//
#include <hip/hip_runtime.h>

#define BB 4
#define SS 2048
#define DD 64
#define HH 16
#define HDD 4
#define NBH (BB*HH)          // 64 (b,h) pairs
#define NROWS (BB*SS)        // 8192
#define NQ (NBH*SS)          // 131072 query rows
#define QTILES 8             // SS/256 (for combine kernel)
#define LOG2E_HALF 0.7213475204444817f  // log2(e)*0.5 (1/sqrt(HD) folded into K)

// native 2-wide fp32 vector: compiler lowers fma on this to v_pk_fma_f32
// (gfx90a+ packed-FP32), inserting required hazard wait-states itself.
typedef float f32x2 __attribute__((ext_vector_type(2)));

// ---------------- Kernel 1: QKV projection + ReLU --------------------------
// Q -> [bh][s][4].  K,V -> pair-transposed KV[bh][s/2][16]:
//   {k0x,k1x, k0y,k1y, k0z,k1z, k0w,k1w, v0x,v1x, ..., v0w,v1w}
// K is prescaled by log2(e)/2.
__global__ __launch_bounds__(256) void qkv_kernel(
    const float* __restrict__ x,
    const float* __restrict__ Wq, const float* __restrict__ bq,
    const float* __restrict__ Wk, const float* __restrict__ bk,
    const float* __restrict__ Wv, const float* __restrict__ bv,
    float* __restrict__ Q, float* __restrict__ KV)
{
    __shared__ float xs[4 * 64];
    const int tid = threadIdx.x;
    const int row0 = blockIdx.x * 4;

    xs[tid] = x[(size_t)row0 * 64 + tid];
    __syncthreads();

    const int r = tid >> 6;
    const int c = tid & 63;
    const int row = row0 + r;
    const int b = row >> 11;
    const int s = row & (SS - 1);
    const float* xr = &xs[r * 64];

    float aq = bq[c], ak = bk[c], av = bv[c];
    #pragma unroll 16
    for (int k = 0; k < 64; ++k) {
        const float xv = xr[k];
        aq = fmaf(xv, Wq[k * 64 + c], aq);
        ak = fmaf(xv, Wk[k * 64 + c], ak);
        av = fmaf(xv, Wv[k * 64 + c], av);
    }
    aq = fmaxf(aq, 0.0f);
    ak = fmaxf(ak, 0.0f) * LOG2E_HALF;   // fold softmax scale+log2e into K
    av = fmaxf(av, 0.0f);

    const int h = c >> 2, hd = c & 3;
    const size_t bhs = ((size_t)(b * HH + h) * SS + s);
    Q[bhs * 4 + hd] = aq;

    const int p = s >> 1, po = s & 1;
    const size_t pb = ((size_t)(b * HH + h) * (SS / 2) + p) * 16;
    KV[pb + hd * 2 + po] = ak;
    KV[pb + 8 + hd * 2 + po] = av;
}

// ---------------- Kernel 2: attention (LDS-staged KV + QROWS=4) ------------
// Per-block KV chunk (8 KB at KSPLIT=8) staged into LDS (coalesced float4),
// inner loop reads it broadcast (no conflicts). QROWS query rows per thread
// share each 64B read: LDS-pipe demand per VALU-cycle halves vs QROWS=2,
// putting the LDS pipe back under budget (R10 showed it oversubscribed).
// No max-subtraction (relu'd inputs, HD=4: scores bounded, exp2 safe).
template<int KSPLIT, int QROWS, bool DIRECT>
__global__ __launch_bounds__(256) void attn_kernel(
    const float* __restrict__ Qb, const float* __restrict__ KVb,
    const float* __restrict__ x, float* __restrict__ y,
    float* __restrict__ accS, float* __restrict__ sumS)
{
    constexpr int QT = SS / (256 * QROWS);   // q-tiles per bh
    constexpr int PAIRS = SS / 2 / KSPLIT;
    __shared__ float4 kvs4[PAIRS * 4];       // PAIRS*64 bytes
    const f32x2* kvs = (const f32x2*)kvs4;

    const int tid = threadIdx.x;
    int blk = blockIdx.x;
    const int ks = blk / (NBH * QT);
    blk -= ks * (NBH * QT);
    const int bh = blk / QT;
    const int qt = blk - bh * QT;

    const float4* kvg = (const float4*)(KVb + ((size_t)bh * (SS / 2) + (size_t)ks * PAIRS) * 16);
    #pragma unroll
    for (int i = 0; i < PAIRS * 4 / 256; ++i)
        kvs4[i * 256 + tid] = kvg[i * 256 + tid];

    f32x2 qx[QROWS], qy[QROWS], qz[QROWS], qw[QROWS];
    #pragma unroll
    for (int r = 0; r < QROWS; ++r) {
        const int qrow = qt * (256 * QROWS) + r * 256 + tid;
        const float4 q = ((const float4*)Qb)[(size_t)bh * SS + qrow];
        qx[r] = {q.x, q.x}; qy[r] = {q.y, q.y};
        qz[r] = {q.z, q.z}; qw[r] = {q.w, q.w};
    }

    f32x2 acx[QROWS], acy[QROWS], acz[QROWS], acw[QROWS], sm[QROWS];
    #pragma unroll
    for (int r = 0; r < QROWS; ++r) {
        acx[r] = {0.f, 0.f}; acy[r] = {0.f, 0.f};
        acz[r] = {0.f, 0.f}; acw[r] = {0.f, 0.f};
        sm[r] = {0.f, 0.f};
    }

    __syncthreads();

    #pragma unroll 2
    for (int j = 0; j < PAIRS; ++j) {
        const f32x2 kx = kvs[j * 8 + 0];   // broadcast LDS reads
        const f32x2 ky = kvs[j * 8 + 1];
        const f32x2 kz = kvs[j * 8 + 2];
        const f32x2 kw = kvs[j * 8 + 3];
        const f32x2 vx = kvs[j * 8 + 4];
        const f32x2 vy = kvs[j * 8 + 5];
        const f32x2 vz = kvs[j * 8 + 6];
        const f32x2 vw = kvs[j * 8 + 7];
        #pragma unroll
        for (int r = 0; r < QROWS; ++r) {
            f32x2 s = qx[r] * kx;
            s = __builtin_elementwise_fma(qy[r], ky, s);
            s = __builtin_elementwise_fma(qz[r], kz, s);
            s = __builtin_elementwise_fma(qw[r], kw, s);
            f32x2 e;
            e.x = __builtin_amdgcn_exp2f(s.x);
            e.y = __builtin_amdgcn_exp2f(s.y);
            sm[r] += e;
            acx[r] = __builtin_elementwise_fma(e, vx, acx[r]);
            acy[r] = __builtin_elementwise_fma(e, vy, acy[r]);
            acz[r] = __builtin_elementwise_fma(e, vz, acz[r]);
            acw[r] = __builtin_elementwise_fma(e, vw, acw[r]);
        }
    }

    #pragma unroll
    for (int r = 0; r < QROWS; ++r) {
        const int qrow = qt * (256 * QROWS) + r * 256 + tid;
        const float sum = sm[r].x + sm[r].y;
        float4 acc = {acx[r].x + acx[r].y, acy[r].x + acy[r].y,
                      acz[r].x + acz[r].y, acw[r].x + acw[r].y};
        if (DIRECT) {
            const float inv = 1.0f / sum;
            const int b = bh >> 4, h = bh & 15;
            const size_t o = ((size_t)(b * SS + qrow)) * DD + h * HDD;
            const float4 xr = *(const float4*)(x + o);
            float4 out;
            out.x = fmaf(acc.x, inv, xr.x);
            out.y = fmaf(acc.y, inv, xr.y);
            out.z = fmaf(acc.z, inv, xr.z);
            out.w = fmaf(acc.w, inv, xr.w);
            *(float4*)(y + o) = out;
        } else {
            const size_t qi = (size_t)ks * NQ + (size_t)bh * SS + qrow;
            ((float4*)accS)[qi] = acc;
            sumS[qi] = sum;
        }
    }
}

// ---------------- Kernel 3: combine partials + residual + BN partials ------
template<int KSPLIT>
__global__ __launch_bounds__(256) void combine_bn(
    const float* __restrict__ accS, const float* __restrict__ sumS,
    const float* __restrict__ x, float* __restrict__ y,
    float* __restrict__ part2)
{
    __shared__ float r[4][8];
    const int tid = threadIdx.x;
    const int bh = blockIdx.x >> 3;
    const int qt = blockIdx.x & 7;
    const int qrow = qt * 256 + tid;
    const size_t qi = (size_t)bh * SS + qrow;

    float4 a = ((const float4*)accS)[qi];
    float s = sumS[qi];
    #pragma unroll
    for (int k = 1; k < KSPLIT; ++k) {
        const float4 a2 = ((const float4*)accS)[(size_t)k * NQ + qi];
        a.x += a2.x; a.y += a2.y; a.z += a2.z; a.w += a2.w;
        s += sumS[(size_t)k * NQ + qi];
    }
    const float inv = 1.0f / s;
    const int b = bh >> 4, h = bh & 15;
    const size_t o = ((size_t)(b * SS + qrow)) * DD + h * HDD;
    const float4 xr = *(const float4*)(x + o);
    float4 out;
    out.x = fmaf(a.x, inv, xr.x);
    out.y = fmaf(a.y, inv, xr.y);
    out.z = fmaf(a.z, inv, xr.z);
    out.w = fmaf(a.w, inv, xr.w);
    *(float4*)(y + o) = out;

    float v[8] = {out.x, out.y, out.z, out.w,
                  out.x * out.x, out.y * out.y, out.z * out.z, out.w * out.w};
    #pragma unroll
    for (int i = 0; i < 8; ++i) {
        float t = v[i];
        for (int off = 32; off > 0; off >>= 1) t += __shfl_down(t, off);
        v[i] = t;
    }
    const int wid = tid >> 6;
    if ((tid & 63) == 0) {
        #pragma unroll
        for (int i = 0; i < 8; ++i) r[wid][i] = v[i];
    }
    __syncthreads();
    if (tid < 8) {
        const float t = r[0][tid] + r[1][tid] + r[2][tid] + r[3][tid];
        const int slot = b * 8 + qt;
        const int i = tid & 3;
        const int c = h * 4 + i;
        if (tid < 4) part2[c * 32 + slot] = t;
        else         part2[2048 + c * 32 + slot] = t;
    }
}

// ---------------- Kernel 4: fused BN stats + normalize ---------------------
__global__ __launch_bounds__(256) void bn_norm_fused(
    float* __restrict__ y, const float* __restrict__ part2,
    const float* __restrict__ gamma, const float* __restrict__ beta)
{
    __shared__ float st[128];
    const int tid = threadIdx.x;
    if (tid < 128) {
        const int c = tid & 63;
        const float* p = part2 + (tid >> 6) * 2048 + c * 32;
        float s = 0.f;
        #pragma unroll
        for (int i = 0; i < 32; ++i) s += p[i];
        st[tid] = s;
    }
    __syncthreads();

    const int idx = blockIdx.x * 256 + tid;          // float4 index
    const int c0 = (idx & 15) * 4;
    float4 v = ((const float4*)y)[idx];
    const float n = 1.0f / NROWS;
    const float m0 = st[c0] * n,     m1 = st[c0 + 1] * n;
    const float m2 = st[c0 + 2] * n, m3 = st[c0 + 3] * n;
    const float r0 = rsqrtf(st[64 + c0] * n - m0 * m0 + 1e-5f);
    const float r1 = rsqrtf(st[65 + c0] * n - m1 * m1 + 1e-5f);
    const float r2 = rsqrtf(st[66 + c0] * n - m2 * m2 + 1e-5f);
    const float r3 = rsqrtf(st[67 + c0] * n - m3 * m3 + 1e-5f);
    float4 o;
    o.x = fmaf((v.x - m0) * r0, gamma[c0],     beta[c0]);
    o.y = fmaf((v.y - m1) * r1, gamma[c0 + 1], beta[c0 + 1]);
    o.z = fmaf((v.z - m2) * r2, gamma[c0 + 2], beta[c0 + 2]);
    o.w = fmaf((v.w - m3) * r3, gamma[c0 + 3], beta[c0 + 3]);
    ((float4*)y)[idx] = o;
}

// ---------------- Fallback BN reduce (tiny-workspace path) -----------------
__global__ __launch_bounds__(256) void bn_reduce1(
    const float* __restrict__ y, float* __restrict__ part)
{
    __shared__ float ls[256], ls2[256];
    const int tid = threadIdx.x;
    const int c = tid & 63;
    const int rg = tid >> 6;
    const int row0 = blockIdx.x * 32 + rg * 8;
    float s = 0.0f, s2 = 0.0f;
    #pragma unroll
    for (int i = 0; i < 8; ++i) {
        const float v = y[(size_t)(row0 + i) * 64 + c];
        s += v;
        s2 = fmaf(v, v, s2);
    }
    ls[tid] = s; ls2[tid] = s2;
    __syncthreads();
    if (rg == 0) {
        part[blockIdx.x * 64 + c] = ls[c] + ls[64 + c] + ls[128 + c] + ls[192 + c];
        part[256 * 64 + blockIdx.x * 64 + c] = ls2[c] + ls2[64 + c] + ls2[128 + c] + ls2[192 + c];
    }
}

__global__ __launch_bounds__(256) void bn_reduce2(
    const float* __restrict__ part, float* __restrict__ stats)
{
    __shared__ float ls[256], ls2[256];
    const int tid = threadIdx.x;
    const int c = tid & 63;
    const int pg = tid >> 6;
    float s = 0.0f, s2 = 0.0f;
    for (int i = pg; i < 256; i += 4) {
        s  += part[i * 64 + c];
        s2 += part[256 * 64 + i * 64 + c];
    }
    ls[tid] = s; ls2[tid] = s2;
    __syncthreads();
    if (pg == 0) {
        const float ts  = ls[c]  + ls[64 + c]  + ls[128 + c]  + ls[192 + c];
        const float ts2 = ls2[c] + ls2[64 + c] + ls2[128 + c] + ls2[192 + c];
        const float mean = ts * (1.0f / NROWS);
        const float var  = ts2 * (1.0f / NROWS) - mean * mean;
        stats[c] = mean;
        stats[64 + c] = rsqrtf(var + 1e-5f);
    }
}

__global__ __launch_bounds__(256) void bn_norm(
    float* __restrict__ y, const float* __restrict__ stats,
    const float* __restrict__ gamma, const float* __restrict__ beta)
{
    const int idx = blockIdx.x * 256 + threadIdx.x;
    const int c = idx & 63;
    const float v = y[idx];
    y[idx] = fmaf((v - stats[c]) * stats[64 + c], gamma[c], beta[c]);
}

// ---------------------------------------------------------------------------
extern "C" void kernel_launch(void* const* d_in, const int* in_sizes, int n_in,
                              void* d_out, int out_size, void* d_ws, size_t ws_size,
                              hipStream_t stream)
{
    const float* x     = (const float*)d_in[0];
    const float* Wq    = (const float*)d_in[1];
    const float* bq    = (const float*)d_in[2];
    const float* Wk    = (const float*)d_in[3];
    const float* bk    = (const float*)d_in[4];
    const float* Wv    = (const float*)d_in[5];
    const float* bv    = (const float*)d_in[6];
    const float* gamma = (const float*)d_in[7];
    const float* beta  = (const float*)d_in[8];
    float* out = (float*)d_out;

    float* ws = (float*)d_ws;
    float* Q  = ws;                  // 524288 floats (2 MB)
    float* KV = ws + 524288;         // 1048576 floats (4 MB)

    qkv_kernel<<<NROWS / 4, 256, 0, stream>>>(x, Wq, bq, Wk, bk, Wv, bv, Q, KV);

    const size_t base = 524288 + 1048576;
    auto need = [](int kk) {
        return (size_t)(524288 + 1048576 + (size_t)kk * NQ * 5 + 4096 + 128) * 4;
    };
    constexpr int QR = 4;                      // query rows per thread
    constexpr int QT = SS / (256 * QR);        // 2 q-tiles per bh

    if (ws_size >= need(8)) {
        // 8-way key split: 1024 blocks, 8 KB LDS KV chunk, QR=4
        float* accS  = ws + base;
        float* sumS  = accS + (size_t)8 * NQ * 4;
        float* part2 = sumS + (size_t)8 * NQ;
        attn_kernel<8, QR, false><<<8 * NBH * QT, 256, 0, stream>>>(Q, KV, x, out, accS, sumS);
        combine_bn<8><<<NBH * QTILES, 256, 0, stream>>>(accS, sumS, x, out, part2);
        bn_norm_fused<<<NROWS * DD / 1024, 256, 0, stream>>>(out, part2, gamma, beta);
    } else if (ws_size >= need(4)) {
        float* accS  = ws + base;
        float* sumS  = accS + (size_t)4 * NQ * 4;
        float* part2 = sumS + (size_t)4 * NQ;
        attn_kernel<4, QR, false><<<4 * NBH * QT, 256, 0, stream>>>(Q, KV, x, out, accS, sumS);
        combine_bn<4><<<NBH * QTILES, 256, 0, stream>>>(accS, sumS, x, out, part2);
        bn_norm_fused<<<NROWS * DD / 1024, 256, 0, stream>>>(out, part2, gamma, beta);
    } else if (ws_size >= need(2)) {
        float* accS  = ws + base;
        float* sumS  = accS + (size_t)2 * NQ * 4;
        float* part2 = sumS + (size_t)2 * NQ;
        attn_kernel<2, QR, false><<<2 * NBH * QT, 256, 0, stream>>>(Q, KV, x, out, accS, sumS);
        combine_bn<2><<<NBH * QTILES, 256, 0, stream>>>(accS, sumS, x, out, part2);
        bn_norm_fused<<<NROWS * DD / 1024, 256, 0, stream>>>(out, part2, gamma, beta);
    } else {
        float* part  = ws + base;                      // 32768 floats
        float* stats = part + 32768;                   // 128
        attn_kernel<1, QR, true><<<NBH * QT, 256, 0, stream>>>(Q, KV, x, out, nullptr, nullptr);
        bn_reduce1<<<256, 256, 0, stream>>>(out, part);
        bn_reduce2<<<1, 256, 0, stream>>>(part, stats);
        bn_norm<<<NROWS * DD / 256, 256, 0, stream>>>(out, stats, gamma, beta);
    }
}